// Round 1
// baseline (748.464 us; speedup 1.0000x reference)
//
#include <hip/hip_runtime.h>
#include <hip/hip_bf16.h>
#include <cstdio>

#define F 128

typedef __attribute__((ext_vector_type(4))) float f32x4;
typedef __attribute__((ext_vector_type(4))) unsigned short u16x4;
typedef __attribute__((ext_vector_type(8))) short s16x8;

__device__ inline unsigned short f2bf(float x) {
  unsigned int u = __float_as_uint(x);
  u += 0x7fffu + ((u >> 16) & 1u);   // RNE
  return (unsigned short)(u >> 16);
}

// ---------------- CSR build ----------------
__global__ void hist_kernel(const int* __restrict__ dst, int* __restrict__ counts, int E) {
  int e = blockIdx.x * blockDim.x + threadIdx.x;
  if (e < E) atomicAdd(&counts[dst[e]], 1);
}

__global__ void scan1_kernel(const int* __restrict__ counts, int* __restrict__ rp,
                             int* __restrict__ bsums, int n) {
  __shared__ int sm[1024];
  int t = threadIdx.x;
  int i = blockIdx.x * 1024 + t;
  int v = (i < n) ? counts[i] : 0;
  sm[t] = v;
  __syncthreads();
  int x = v;
  for (int off = 1; off < 1024; off <<= 1) {
    int add = (t >= off) ? sm[t - off] : 0;
    __syncthreads();
    x += add;
    sm[t] = x;
    __syncthreads();
  }
  if (i < n) rp[i] = x - v;            // exclusive
  if (t == 1023) bsums[blockIdx.x] = x; // block total
}

__global__ void scan2_kernel(int* __restrict__ bsums, int nb) {
  if (threadIdx.x == 0 && blockIdx.x == 0) {
    int s = 0;
    for (int i = 0; i < nb; ++i) { int v = bsums[i]; bsums[i] = s; s += v; }
  }
}

__global__ void scan3_kernel(int* __restrict__ rp, int* __restrict__ cursor,
                             const int* __restrict__ bsums, int n, int E) {
  int i = blockIdx.x * 1024 + threadIdx.x;
  if (i < n) { int v = rp[i] + bsums[blockIdx.x]; rp[i] = v; cursor[i] = v; }
  if (i == 0) rp[n] = E;
}

__global__ void scatter_kernel(const int* __restrict__ src, const int* __restrict__ dst,
                               const float* __restrict__ ew, int* __restrict__ cursor,
                               int* __restrict__ csr_src, float* __restrict__ csr_w, int E) {
  int e = blockIdx.x * blockDim.x + threadIdx.x;
  if (e >= E) return;
  int d = dst[e];
  int pos = atomicAdd(&cursor[d], 1);
  csr_src[pos] = src[e];
  csr_w[pos] = ew[e];
}

// ---------------- SPMM: Tout[r] = scale * sum_j w_j * Tin[src_j] - Tsub[r] ----------------
// one wave per dst row; lane covers 2 feature columns (float2)
__global__ void spmm_kernel(const float* __restrict__ Tin, const float* __restrict__ Tsub,
                            float* __restrict__ Tout,
                            const int* __restrict__ rp, const int* __restrict__ csr_src,
                            const float* __restrict__ csr_w, int n, float scale) {
  int row = blockIdx.x * (blockDim.x >> 6) + (threadIdx.x >> 6);
  if (row >= n) return;
  int lane = threadIdx.x & 63;
  int j = rp[row], end = rp[row + 1];
  const float2* Tin2 = (const float2*)Tin;
  float ax = 0.f, ay = 0.f;
  for (; j < end; ++j) {
    int s = csr_src[j];
    float w = csr_w[j];
    float2 v = Tin2[(size_t)s * 64 + lane];
    ax = fmaf(w, v.x, ax);
    ay = fmaf(w, v.y, ay);
  }
  float rx = scale * ax, ry = scale * ay;
  if (Tsub) {
    float2 p = ((const float2*)Tsub)[(size_t)row * 64 + lane];
    rx -= p.x; ry -= p.y;
  }
  float2 o; o.x = rx; o.y = ry;
  ((float2*)Tout)[(size_t)row * 64 + lane] = o;
}

// ---------------- W transpose+convert: Wt[n][k*128 + r] = bf16(W[k][r][n]) ----------------
__global__ void convw_kernel(const float* __restrict__ W, unsigned short* __restrict__ Wt,
                             int total, int Kd) {
  int idx = blockIdx.x * 256 + threadIdx.x;
  if (idx >= total) return;
  int nn = idx / Kd;
  int rem = idx - nn * Kd;  // kk*128 + r
  int kk = rem >> 7;
  int r = rem & 127;
  Wt[idx] = f2bf(W[(size_t)kk * F * F + (size_t)r * F + nn]);
}

// ---------------- fused scale+convert+GEMM ----------------
// out[i,:] = sum_ks fc[ks,i] * (A_ks[i,:] @ W[ks]) + bias
// A (bf16, built on the fly) is M x (K*128); Wt is pre-transposed [128 n][K*128 k]
struct GemmArgs {
  const float* A[8];
  const float* fc;
  const unsigned short* Wt;
  const float* bias;
  float* out;
  int n;
  int kslices;
};

__global__ __launch_bounds__(256) void gemm_kernel(GemmArgs args) {
  __shared__ __align__(16) unsigned short lds_a[128][72];  // +8 pad: 2-way-free banks
  __shared__ __align__(16) unsigned short lds_b[128][72];
  const int t = threadIdx.x;
  const int lane = t & 63;
  const int wid = t >> 6;
  const int wrow = wid >> 1, wcol = wid & 1;  // 2x2 waves, each 64x64
  const int bm = blockIdx.x * 128;
  const int n = args.n;
  const int kiters = args.kslices * 2;        // BK=64
  const int pitchW = args.kslices * 128;

  const int srow = t >> 4;        // 0..15
  const int scol = (t & 15) * 4;  // 0..60

  f32x4 acc[4][4];
#pragma unroll
  for (int a = 0; a < 4; ++a)
#pragma unroll
    for (int b = 0; b < 4; ++b) acc[a][b] = (f32x4){0.f, 0.f, 0.f, 0.f};

  for (int it = 0; it < kiters; ++it) {
    __syncthreads();
    const int ks = it >> 1;
    const float* As = args.A[ks];
    const float* fcs = args.fc + (size_t)ks * n;
    const int cbase = (it & 1) * 64 + scol;
#pragma unroll
    for (int i = 0; i < 8; ++i) {
      int r = srow + 16 * i;
      int rg = bm + r;
      int rc = rg < n ? rg : n - 1;
      f32x4 v = *(const f32x4*)(As + (size_t)rc * F + cbase);
      float f = fcs[rc];
      u16x4 sv;
      sv.x = f2bf(v.x * f);
      sv.y = f2bf(v.y * f);
      sv.z = f2bf(v.z * f);
      sv.w = f2bf(v.w * f);
      *(u16x4*)&lds_a[r][scol] = sv;
    }
    {
      const unsigned short* Ws = args.Wt + it * 64;
#pragma unroll
      for (int i = 0; i < 8; ++i) {
        int r = srow + 16 * i;
        u16x4 w = *(const u16x4*)(Ws + (size_t)r * pitchW + scol);
        *(u16x4*)&lds_b[r][scol] = w;
      }
    }
    __syncthreads();
#pragma unroll
    for (int kk = 0; kk < 2; ++kk) {
      s16x8 af[4], bfr[4];
#pragma unroll
      for (int mt = 0; mt < 4; ++mt)
        af[mt] = *(const s16x8*)&lds_a[wrow * 64 + mt * 16 + (lane & 15)][kk * 32 + (lane >> 4) * 8];
#pragma unroll
      for (int nt = 0; nt < 4; ++nt)
        bfr[nt] = *(const s16x8*)&lds_b[wcol * 64 + nt * 16 + (lane & 15)][kk * 32 + (lane >> 4) * 8];
#pragma unroll
      for (int mt = 0; mt < 4; ++mt)
#pragma unroll
        for (int nt = 0; nt < 4; ++nt)
          acc[mt][nt] = __builtin_amdgcn_mfma_f32_16x16x32_bf16(af[mt], bfr[nt], acc[mt][nt], 0, 0, 0);
    }
  }

  // epilogue: C/D layout col=lane&15, row=(lane>>4)*4+reg
#pragma unroll
  for (int nt = 0; nt < 4; ++nt) {
    int col = wcol * 64 + nt * 16 + (lane & 15);
    float bv = args.bias[col];
#pragma unroll
    for (int mt = 0; mt < 4; ++mt) {
#pragma unroll
      for (int r4 = 0; r4 < 4; ++r4) {
        int row = bm + wrow * 64 + mt * 16 + (lane >> 4) * 4 + r4;
        if (row < n) args.out[(size_t)row * F + col] = acc[mt][nt][r4] + bv;
      }
    }
  }
}

extern "C" void kernel_launch(void* const* d_in, const int* in_sizes, int n_in,
                              void* d_out, int out_size, void* d_ws, size_t ws_size,
                              hipStream_t stream) {
  const float* x    = (const float*)d_in[0];
  const float* fc   = (const float*)d_in[1];
  const float* W    = (const float*)d_in[2];
  const float* bias = (const float*)d_in[3];
  const float* ew   = (const float*)d_in[4];
  const int*   src  = (const int*)d_in[5];
  const int*   dst  = (const int*)d_in[6];

  const int N = in_sizes[0] / F;
  const int K = in_sizes[2] / (F * F);
  const int E = in_sizes[4];

  size_t off = 0;
  char* base = (char*)d_ws;
  auto alloc = [&](size_t bytes) -> void* {
    void* p = base + off;
    off += (bytes + 511) & ~(size_t)511;
    return p;
  };
  int* cursor          = (int*)alloc((size_t)N * 4);
  int* rp              = (int*)alloc(((size_t)N + 1) * 4);
  int* bsums           = (int*)alloc(4096);
  int* csr_src         = (int*)alloc((size_t)E * 4);
  float* csr_w         = (float*)alloc((size_t)E * 4);
  unsigned short* Wt   = (unsigned short*)alloc((size_t)K * F * F * 2);
  float* T[8];
  T[0] = nullptr;
  for (int k = 1; k < K && k < 8; ++k) T[k] = (float*)alloc((size_t)N * F * 4);
  if (off > ws_size) {
    fprintf(stderr, "kernel_launch: ws too small: need %zu have %zu\n", off, ws_size);
    return;
  }

  // ---- CSR build ----
  hipMemsetAsync(cursor, 0, (size_t)N * 4, stream);
  int hb = (E + 255) / 256;
  hipLaunchKernelGGL(hist_kernel, dim3(hb), dim3(256), 0, stream, dst, cursor, E);
  int nb = (N + 1023) / 1024;
  hipLaunchKernelGGL(scan1_kernel, dim3(nb), dim3(1024), 0, stream, cursor, rp, bsums, N);
  hipLaunchKernelGGL(scan2_kernel, dim3(1), dim3(64), 0, stream, bsums, nb);
  hipLaunchKernelGGL(scan3_kernel, dim3(nb), dim3(1024), 0, stream, rp, cursor, bsums, N, E);
  hipLaunchKernelGGL(scatter_kernel, dim3(hb), dim3(256), 0, stream, src, dst, ew, cursor,
                     csr_src, csr_w, E);

  // ---- Chebyshev recurrence (fp32) ----
  int sb = (N + 3) / 4;  // 4 rows (waves) per 256-thread block
  if (K > 1)
    hipLaunchKernelGGL(spmm_kernel, dim3(sb), dim3(256), 0, stream, x, (const float*)nullptr,
                       T[1], rp, csr_src, csr_w, N, 1.0f);
  for (int k = 2; k < K; ++k) {
    const float* prev = (k == 2) ? x : T[k - 2];
    hipLaunchKernelGGL(spmm_kernel, dim3(sb), dim3(256), 0, stream, T[k - 1], prev, T[k],
                       rp, csr_src, csr_w, N, 2.0f);
  }

  // ---- W transpose+convert ----
  int total = K * F * F;
  hipLaunchKernelGGL(convw_kernel, dim3((total + 255) / 256), dim3(256), 0, stream, W, Wt,
                     total, K * F);

  // ---- fused GEMM ----
  GemmArgs ga;
  ga.A[0] = x;
  for (int k = 1; k < 8; ++k) ga.A[k] = (k < K) ? T[k] : x;
  ga.fc = fc; ga.Wt = Wt; ga.bias = bias;
  ga.out = (float*)d_out;
  ga.n = N; ga.kslices = K;
  hipLaunchKernelGGL(gemm_kernel, dim3((N + 127) / 128), dim3(256), 0, stream, ga);
}

// Round 2
// 478.334 us; speedup vs baseline: 1.5647x; 1.5647x over previous
//
#include <hip/hip_runtime.h>
#include <hip/hip_bf16.h>
#include <cstdio>

#define F 128

typedef __attribute__((ext_vector_type(4))) float f32x4;
typedef __attribute__((ext_vector_type(4))) unsigned short u16x4;
typedef __attribute__((ext_vector_type(8))) short s16x8;

__device__ inline unsigned short f2bf(float x) {
  unsigned int u = __float_as_uint(x);
  u += 0x7fffu + ((u >> 16) & 1u);   // RNE
  return (unsigned short)(u >> 16);
}
__device__ inline float bf2f(unsigned int h) {
  return __uint_as_float(h << 16);
}

// ---------------- CSR build ----------------
__global__ void hist_kernel(const int* __restrict__ dst, int* __restrict__ counts, int E) {
  int e = blockIdx.x * blockDim.x + threadIdx.x;
  if (e < E) atomicAdd(&counts[dst[e]], 1);
}

__global__ void scan1_kernel(const int* __restrict__ counts, int* __restrict__ rp,
                             int* __restrict__ bsums, int n) {
  __shared__ int sm[1024];
  int t = threadIdx.x;
  int i = blockIdx.x * 1024 + t;
  int v = (i < n) ? counts[i] : 0;
  sm[t] = v;
  __syncthreads();
  int x = v;
  for (int off = 1; off < 1024; off <<= 1) {
    int add = (t >= off) ? sm[t - off] : 0;
    __syncthreads();
    x += add;
    sm[t] = x;
    __syncthreads();
  }
  if (i < n) rp[i] = x - v;            // exclusive
  if (t == 1023) bsums[blockIdx.x] = x; // block total
}

// one-block parallel exclusive scan of bsums (nb <= 1024)
__global__ void scan2_kernel(int* __restrict__ bsums, int nb) {
  __shared__ int sm[1024];
  int t = threadIdx.x;
  int v = (t < nb) ? bsums[t] : 0;
  sm[t] = v;
  __syncthreads();
  int x = v;
  for (int off = 1; off < 1024; off <<= 1) {
    int add = (t >= off) ? sm[t - off] : 0;
    __syncthreads();
    x += add;
    sm[t] = x;
    __syncthreads();
  }
  if (t < nb) bsums[t] = x - v;
}

__global__ void scan3_kernel(int* __restrict__ rp, int* __restrict__ cursor,
                             const int* __restrict__ bsums, int n, int E) {
  int i = blockIdx.x * 1024 + threadIdx.x;
  if (i < n) { int v = rp[i] + bsums[blockIdx.x]; rp[i] = v; cursor[i] = v; }
  if (i == 0) rp[n] = E;
}

__global__ void scatter_kernel(const int* __restrict__ src, const int* __restrict__ dst,
                               const float* __restrict__ ew, int* __restrict__ cursor,
                               int2* __restrict__ csr, int E) {
  int e = blockIdx.x * blockDim.x + threadIdx.x;
  if (e >= E) return;
  int d = dst[e];
  int pos = atomicAdd(&cursor[d], 1);
  int2 sw;
  sw.x = src[e];
  sw.y = __float_as_int(ew[e]);
  csr[pos] = sw;
}

// ---------------- x fp32 -> bf16 ----------------
__global__ void convx_kernel(const float* __restrict__ x, unsigned short* __restrict__ xbf,
                             int total4) {
  int i = blockIdx.x * 256 + threadIdx.x;
  if (i >= total4) return;
  f32x4 v = ((const f32x4*)x)[i];
  u16x4 o;
  o.x = f2bf(v.x); o.y = f2bf(v.y); o.z = f2bf(v.z); o.w = f2bf(v.w);
  ((u16x4*)xbf)[i] = o;
}

// ---------------- SPMM (bf16 state, fp32 accum) ----------------
// Tout[r] = bf16( scale * sum_j w_j * Tin[src_j] - Tsub[r] )
// one wave per dst row; lane covers 2 bf16 columns (4B)
__global__ void spmm_kernel(const unsigned short* __restrict__ Tin,
                            const unsigned short* __restrict__ Tsub,
                            unsigned short* __restrict__ Tout,
                            const int* __restrict__ rp, const int2* __restrict__ csr,
                            int n, float scale) {
  int row = blockIdx.x * (blockDim.x >> 6) + (threadIdx.x >> 6);
  if (row >= n) return;
  int lane = threadIdx.x & 63;
  int j = rp[row], end = rp[row + 1];
  float ax = 0.f, ay = 0.f;
  const int co = lane * 2;

  for (; j + 4 <= end; j += 4) {
    int2 e0 = csr[j], e1 = csr[j + 1], e2 = csr[j + 2], e3 = csr[j + 3];
    unsigned int v0 = *(const unsigned int*)(Tin + (size_t)e0.x * F + co);
    unsigned int v1 = *(const unsigned int*)(Tin + (size_t)e1.x * F + co);
    unsigned int v2 = *(const unsigned int*)(Tin + (size_t)e2.x * F + co);
    unsigned int v3 = *(const unsigned int*)(Tin + (size_t)e3.x * F + co);
    float w0 = __int_as_float(e0.y), w1 = __int_as_float(e1.y);
    float w2 = __int_as_float(e2.y), w3 = __int_as_float(e3.y);
    ax = fmaf(w0, bf2f(v0 & 0xffffu), ax); ay = fmaf(w0, bf2f(v0 >> 16), ay);
    ax = fmaf(w1, bf2f(v1 & 0xffffu), ax); ay = fmaf(w1, bf2f(v1 >> 16), ay);
    ax = fmaf(w2, bf2f(v2 & 0xffffu), ax); ay = fmaf(w2, bf2f(v2 >> 16), ay);
    ax = fmaf(w3, bf2f(v3 & 0xffffu), ax); ay = fmaf(w3, bf2f(v3 >> 16), ay);
  }
  for (; j < end; ++j) {
    int2 e = csr[j];
    unsigned int v = *(const unsigned int*)(Tin + (size_t)e.x * F + co);
    float w = __int_as_float(e.y);
    ax = fmaf(w, bf2f(v & 0xffffu), ax); ay = fmaf(w, bf2f(v >> 16), ay);
  }

  float rx = scale * ax, ry = scale * ay;
  if (Tsub) {
    unsigned int p = *(const unsigned int*)(Tsub + (size_t)row * F + co);
    rx -= bf2f(p & 0xffffu);
    ry -= bf2f(p >> 16);
  }
  unsigned int o = (unsigned int)f2bf(rx) | ((unsigned int)f2bf(ry) << 16);
  *(unsigned int*)(Tout + (size_t)row * F + co) = o;
}

// ---------------- W transpose+convert: Wt[n][k*128 + r] = bf16(W[k][r][n]) ----------------
__global__ void convw_kernel(const float* __restrict__ W, unsigned short* __restrict__ Wt,
                             int total, int Kd) {
  int idx = blockIdx.x * 256 + threadIdx.x;
  if (idx >= total) return;
  int nn = idx / Kd;
  int rem = idx - nn * Kd;  // kk*128 + r
  int kk = rem >> 7;
  int r = rem & 127;
  Wt[idx] = f2bf(W[(size_t)kk * F * F + (size_t)r * F + nn]);
}

// ---------------- fused scale+GEMM ----------------
// out[i,:] = sum_ks fc[ks,i] * (A_ks[i,:] @ W[ks]) + bias
// A slices are bf16 [n][128]; Wt is pre-transposed bf16 [128 n][K*128 k]
struct GemmArgs {
  const unsigned short* A[8];
  const float* fc;
  const unsigned short* Wt;
  const float* bias;
  float* out;
  int n;
  int kslices;
};

__global__ __launch_bounds__(256) void gemm_kernel(GemmArgs args) {
  __shared__ __align__(16) unsigned short lds_a[128][72];  // +8 pad
  __shared__ __align__(16) unsigned short lds_b[128][72];
  const int t = threadIdx.x;
  const int lane = t & 63;
  const int wid = t >> 6;
  const int wrow = wid >> 1, wcol = wid & 1;  // 2x2 waves, each 64x64
  const int bm = blockIdx.x * 128;
  const int n = args.n;
  const int kiters = args.kslices * 2;        // BK=64
  const int pitchW = args.kslices * 128;

  const int srow = t >> 4;        // 0..15
  const int scol = (t & 15) * 4;  // 0..60

  f32x4 acc[4][4];
#pragma unroll
  for (int a = 0; a < 4; ++a)
#pragma unroll
    for (int b = 0; b < 4; ++b) acc[a][b] = (f32x4){0.f, 0.f, 0.f, 0.f};

  for (int it = 0; it < kiters; ++it) {
    __syncthreads();
    const int ks = it >> 1;
    const unsigned short* As = args.A[ks];
    const float* fcs = args.fc + (size_t)ks * n;
    const int cbase = (it & 1) * 64 + scol;
#pragma unroll
    for (int i = 0; i < 8; ++i) {
      int r = srow + 16 * i;
      int rg = bm + r;
      int rc = rg < n ? rg : n - 1;
      u16x4 v = *(const u16x4*)(As + (size_t)rc * F + cbase);
      float f = fcs[rc];
      u16x4 sv;
      sv.x = f2bf(bf2f(v.x) * f);
      sv.y = f2bf(bf2f(v.y) * f);
      sv.z = f2bf(bf2f(v.z) * f);
      sv.w = f2bf(bf2f(v.w) * f);
      *(u16x4*)&lds_a[r][scol] = sv;
    }
    {
      const unsigned short* Ws = args.Wt + it * 64;
#pragma unroll
      for (int i = 0; i < 8; ++i) {
        int r = srow + 16 * i;
        u16x4 w = *(const u16x4*)(Ws + (size_t)r * pitchW + scol);
        *(u16x4*)&lds_b[r][scol] = w;
      }
    }
    __syncthreads();
#pragma unroll
    for (int kk = 0; kk < 2; ++kk) {
      s16x8 af[4], bfr[4];
#pragma unroll
      for (int mt = 0; mt < 4; ++mt)
        af[mt] = *(const s16x8*)&lds_a[wrow * 64 + mt * 16 + (lane & 15)][kk * 32 + (lane >> 4) * 8];
#pragma unroll
      for (int nt = 0; nt < 4; ++nt)
        bfr[nt] = *(const s16x8*)&lds_b[wcol * 64 + nt * 16 + (lane & 15)][kk * 32 + (lane >> 4) * 8];
#pragma unroll
      for (int mt = 0; mt < 4; ++mt)
#pragma unroll
        for (int nt = 0; nt < 4; ++nt)
          acc[mt][nt] = __builtin_amdgcn_mfma_f32_16x16x32_bf16(af[mt], bfr[nt], acc[mt][nt], 0, 0, 0);
    }
  }

  // epilogue: C/D layout col=lane&15, row=(lane>>4)*4+reg
#pragma unroll
  for (int nt = 0; nt < 4; ++nt) {
    int col = wcol * 64 + nt * 16 + (lane & 15);
    float bv = args.bias[col];
#pragma unroll
    for (int mt = 0; mt < 4; ++mt) {
#pragma unroll
      for (int r4 = 0; r4 < 4; ++r4) {
        int row = bm + wrow * 64 + mt * 16 + (lane >> 4) * 4 + r4;
        if (row < n) args.out[(size_t)row * F + col] = acc[mt][nt][r4] + bv;
      }
    }
  }
}

extern "C" void kernel_launch(void* const* d_in, const int* in_sizes, int n_in,
                              void* d_out, int out_size, void* d_ws, size_t ws_size,
                              hipStream_t stream) {
  const float* x    = (const float*)d_in[0];
  const float* fc   = (const float*)d_in[1];
  const float* W    = (const float*)d_in[2];
  const float* bias = (const float*)d_in[3];
  const float* ew   = (const float*)d_in[4];
  const int*   src  = (const int*)d_in[5];
  const int*   dst  = (const int*)d_in[6];

  const int N = in_sizes[0] / F;
  const int K = in_sizes[2] / (F * F);
  const int E = in_sizes[4];

  size_t off = 0;
  char* base = (char*)d_ws;
  auto alloc = [&](size_t bytes) -> void* {
    void* p = base + off;
    off += (bytes + 511) & ~(size_t)511;
    return p;
  };
  int* cursor          = (int*)alloc((size_t)N * 4);
  int* rp              = (int*)alloc(((size_t)N + 1) * 4);
  int* bsums           = (int*)alloc(4096);
  int2* csr            = (int2*)alloc((size_t)E * 8);
  unsigned short* Wt   = (unsigned short*)alloc((size_t)K * F * F * 2);
  unsigned short* xbf  = (unsigned short*)alloc((size_t)N * F * 2);
  unsigned short* T[8];
  T[0] = xbf;
  for (int k = 1; k < K && k < 8; ++k) T[k] = (unsigned short*)alloc((size_t)N * F * 2);
  if (off > ws_size) {
    fprintf(stderr, "kernel_launch: ws too small: need %zu have %zu\n", off, ws_size);
    return;
  }

  // ---- CSR build ----
  hipMemsetAsync(cursor, 0, (size_t)N * 4, stream);
  int hb = (E + 255) / 256;
  hipLaunchKernelGGL(hist_kernel, dim3(hb), dim3(256), 0, stream, dst, cursor, E);
  int nb = (N + 1023) / 1024;
  hipLaunchKernelGGL(scan1_kernel, dim3(nb), dim3(1024), 0, stream, cursor, rp, bsums, N);
  hipLaunchKernelGGL(scan2_kernel, dim3(1), dim3(1024), 0, stream, bsums, nb);
  hipLaunchKernelGGL(scan3_kernel, dim3(nb), dim3(1024), 0, stream, rp, cursor, bsums, N, E);
  hipLaunchKernelGGL(scatter_kernel, dim3(hb), dim3(256), 0, stream, src, dst, ew, cursor,
                     csr, E);

  // ---- x -> bf16 ----
  int total4 = N * F / 4;
  hipLaunchKernelGGL(convx_kernel, dim3((total4 + 255) / 256), dim3(256), 0, stream,
                     x, xbf, total4);

  // ---- Chebyshev recurrence (bf16 state, fp32 accum) ----
  int sb = (N + 3) / 4;  // 4 rows (waves) per 256-thread block
  if (K > 1)
    hipLaunchKernelGGL(spmm_kernel, dim3(sb), dim3(256), 0, stream, xbf,
                       (const unsigned short*)nullptr, T[1], rp, csr, N, 1.0f);
  for (int k = 2; k < K; ++k) {
    const unsigned short* prev = T[k - 2];
    hipLaunchKernelGGL(spmm_kernel, dim3(sb), dim3(256), 0, stream, T[k - 1], prev, T[k],
                       rp, csr, N, 2.0f);
  }

  // ---- W transpose+convert ----
  int total = K * F * F;
  hipLaunchKernelGGL(convw_kernel, dim3((total + 255) / 256), dim3(256), 0, stream, W, Wt,
                     total, K * F);

  // ---- fused GEMM ----
  GemmArgs ga;
  for (int k = 0; k < 8; ++k) ga.A[k] = (k < K) ? T[k] : xbf;
  ga.fc = fc; ga.Wt = Wt; ga.bias = bias;
  ga.out = (float*)d_out;
  ga.n = N; ga.kslices = K;
  hipLaunchKernelGGL(gemm_kernel, dim3((N + 127) / 128), dim3(256), 0, stream, ga);
}

// Round 3
// 354.335 us; speedup vs baseline: 2.1123x; 1.3500x over previous
//
#include <hip/hip_runtime.h>
#include <hip/hip_bf16.h>
#include <cstdio>

#define F 128
#define BSHIFT 9
#define BROWS 512   // rows per bucket (N must be <= 131072 for the 17-bit src pack)
#define C2 4096     // edges per bucket_scatter block

typedef __attribute__((ext_vector_type(4))) float f32x4;
typedef __attribute__((ext_vector_type(4))) unsigned short u16x4;
typedef __attribute__((ext_vector_type(8))) short s16x8;

__device__ inline unsigned short f2bf(float x) {
  unsigned int u = __float_as_uint(x);
  u += 0x7fffu + ((u >> 16) & 1u);   // RNE
  return (unsigned short)(u >> 16);
}
__device__ inline float bf2f(unsigned int h) {
  return __uint_as_float(h << 16);
}

// ---------------- bucket histogram (LDS-aggregated) ----------------
__global__ void bucket_hist_kernel(const int* __restrict__ dst, int* __restrict__ bhist,
                                   int E, int B) {
  __shared__ int h[256];
  int t = threadIdx.x;
  h[t] = 0;
  __syncthreads();
  for (int e = blockIdx.x * blockDim.x + t; e < E; e += gridDim.x * blockDim.x)
    atomicAdd(&h[dst[e] >> BSHIFT], 1);
  __syncthreads();
  if (t < B && h[t]) atomicAdd(&bhist[t], h[t]);
}

// ---------------- bucket scan: bases (== rp at bucket boundaries) ----------------
__global__ void bucket_scan_kernel(const int* __restrict__ bhist, int* __restrict__ bbase,
                                   int* __restrict__ bcursor, int* __restrict__ rp,
                                   int E, int B, int N) {
  __shared__ int sm[256];
  int t = threadIdx.x;
  int v = (t < B) ? bhist[t] : 0;
  sm[t] = v;
  __syncthreads();
  int x = v;
  for (int off = 1; off < 256; off <<= 1) {
    int add = (t >= off) ? sm[t - off] : 0;
    __syncthreads();
    x += add;
    sm[t] = x;
    __syncthreads();
  }
  int excl = x - v;
  if (t < B) { bbase[t] = excl; bcursor[t] = excl; }
  if (t == 0) { bbase[B] = E; rp[N] = E; }
}

// ---------------- grouped bucket scatter: edges -> bucket-major staging ----------------
__global__ __launch_bounds__(256) void bucket_scatter_kernel(
    const int* __restrict__ src, const int* __restrict__ dst, const float* __restrict__ ew,
    int* __restrict__ bcursor, unsigned int* __restrict__ stg_p, float* __restrict__ stg_w,
    int E, int B) {
  __shared__ int hist[256], gbase[256], cur[256], sm[256], scn[256];
  __shared__ unsigned int sp[C2];
  __shared__ float swt[C2];
  __shared__ int sdest[C2];
  int t = threadIdx.x;
  int e0 = blockIdx.x * C2;
  int cnt = min(C2, E - e0);
  hist[t] = 0;
  __syncthreads();
#pragma unroll
  for (int i = 0; i < C2 / 256; ++i) {
    int e = e0 + t + i * 256;
    if (e < E) atomicAdd(&hist[dst[e] >> BSHIFT], 1);
  }
  __syncthreads();
  int v = hist[t];
  gbase[t] = (t < B && v) ? atomicAdd(&bcursor[t], v) : 0;
  sm[t] = v;
  __syncthreads();
  int x = v;
  for (int off = 1; off < 256; off <<= 1) {
    int add = (t >= off) ? sm[t - off] : 0;
    __syncthreads();
    x += add;
    sm[t] = x;
    __syncthreads();
  }
  scn[t] = x - v;
  cur[t] = 0;
  __syncthreads();
#pragma unroll
  for (int i = 0; i < C2 / 256; ++i) {
    int e = e0 + t + i * 256;
    if (e < E) {
      int d = dst[e];
      int b = d >> BSHIFT;
      int r = atomicAdd(&cur[b], 1);
      int slot = scn[b] + r;
      sp[slot] = (unsigned int)src[e] | ((unsigned int)(d & (BROWS - 1)) << 17);
      swt[slot] = ew[e];
      sdest[slot] = gbase[b] + r;
    }
  }
  __syncthreads();
#pragma unroll
  for (int i = 0; i < C2 / 256; ++i) {
    int s = t + i * 256;
    if (s < cnt) {
      int dpos = sdest[s];
      stg_p[dpos] = sp[s];
      stg_w[dpos] = swt[s];
    }
  }
}

// ---------------- per-bucket CSR finalize (also produces rp) ----------------
__global__ __launch_bounds__(256) void csr_build_kernel(
    const unsigned int* __restrict__ stg_p, const float* __restrict__ stg_w,
    const int* __restrict__ bbase, int* __restrict__ rp, int2* __restrict__ csr,
    int N, int B) {
  __shared__ int rhist[BROWS], rloc[BROWS], curp[BROWS];
  __shared__ int sm[256];
  int b = blockIdx.x, t = threadIdx.x;
  int row0 = b << BSHIFT;
  int base = bbase[b];
  int cnt = bbase[b + 1] - base;
  rhist[t] = 0;
  rhist[t + 256] = 0;
  __syncthreads();
  for (int s = base + t; s < base + cnt; s += 256)
    atomicAdd(&rhist[stg_p[s] >> 17], 1);
  __syncthreads();
  int a0 = rhist[2 * t], a1 = rhist[2 * t + 1];
  int pv = a0 + a1;
  sm[t] = pv;
  __syncthreads();
  int x = pv;
  for (int off = 1; off < 256; off <<= 1) {
    int add = (t >= off) ? sm[t - off] : 0;
    __syncthreads();
    x += add;
    sm[t] = x;
    __syncthreads();
  }
  int pexcl = x - pv;
  int r0 = 2 * t, r1 = 2 * t + 1;
  rloc[r0] = pexcl;
  rloc[r1] = pexcl + a0;
  if (row0 + r0 < N) rp[row0 + r0] = base + rloc[r0];
  if (row0 + r1 < N) rp[row0 + r1] = base + rloc[r1];
  curp[r0] = base + rloc[r0];
  curp[r1] = base + rloc[r1];
  __syncthreads();
  for (int s = base + t; s < base + cnt; s += 256) {
    unsigned int p = stg_p[s];
    int dl = p >> 17;
    int pos = atomicAdd(&curp[dl], 1);
    int2 entry;
    entry.x = (int)(p & 0x1ffffu);
    entry.y = __float_as_int(stg_w[s]);
    csr[pos] = entry;   // random 8B but confined to this bucket's ~64KB window
  }
}

// ---------------- x fp32 -> bf16 ----------------
__global__ void convx_kernel(const float* __restrict__ x, unsigned short* __restrict__ xbf,
                             int total4) {
  int i = blockIdx.x * 256 + threadIdx.x;
  if (i >= total4) return;
  f32x4 v = ((const f32x4*)x)[i];
  u16x4 o;
  o.x = f2bf(v.x); o.y = f2bf(v.y); o.z = f2bf(v.z); o.w = f2bf(v.w);
  ((u16x4*)xbf)[i] = o;
}

// ---------------- SPMM: wave = 1 row, 4 edges/iter, 16B/lane gathers ----------------
// Tout[r] = bf16( scale * sum_j w_j * Tin[src_j] - Tsub[r] )
__global__ __launch_bounds__(256) void spmm_kernel(
    const unsigned short* __restrict__ Tin, const unsigned short* __restrict__ Tsub,
    unsigned short* __restrict__ Tout, const int* __restrict__ rp,
    const int2* __restrict__ csr, int n, float scale) {
  int wv = blockIdx.x * (blockDim.x >> 6) + (threadIdx.x >> 6);
  if (wv >= n) return;
  int lane = threadIdx.x & 63;
  int sl = lane & 15;   // 16B column slice
  int eo = lane >> 4;   // which of 4 edges this quarter-wave handles
  int j0 = rp[wv], end = rp[wv + 1];
  const uint4* Tin4 = (const uint4*)Tin;
  float acc[8];
#pragma unroll
  for (int c = 0; c < 8; ++c) acc[c] = 0.f;

  for (int j = j0; j < end; j += 16) {
    int2 e[4];
    float w[4];
    uint4 v[4];
#pragma unroll
    for (int u = 0; u < 4; ++u) {
      int je = j + 4 * u + eo;
      bool live = je < end;
      e[u] = csr[live ? je : end - 1];
      w[u] = live ? __int_as_float(e[u].y) : 0.f;
    }
#pragma unroll
    for (int u = 0; u < 4; ++u) v[u] = Tin4[(size_t)e[u].x * 16 + sl];
#pragma unroll
    for (int u = 0; u < 4; ++u) {
      acc[0] = fmaf(w[u], bf2f(v[u].x & 0xffffu), acc[0]);
      acc[1] = fmaf(w[u], bf2f(v[u].x >> 16), acc[1]);
      acc[2] = fmaf(w[u], bf2f(v[u].y & 0xffffu), acc[2]);
      acc[3] = fmaf(w[u], bf2f(v[u].y >> 16), acc[3]);
      acc[4] = fmaf(w[u], bf2f(v[u].z & 0xffffu), acc[4]);
      acc[5] = fmaf(w[u], bf2f(v[u].z >> 16), acc[5]);
      acc[6] = fmaf(w[u], bf2f(v[u].w & 0xffffu), acc[6]);
      acc[7] = fmaf(w[u], bf2f(v[u].w >> 16), acc[7]);
    }
  }
#pragma unroll
  for (int h = 16; h <= 32; h <<= 1)
#pragma unroll
    for (int c = 0; c < 8; ++c) acc[c] += __shfl_xor(acc[c], h, 64);

  if (eo == 0) {
    float r[8];
#pragma unroll
    for (int c = 0; c < 8; ++c) r[c] = scale * acc[c];
    if (Tsub) {
      uint4 p = ((const uint4*)Tsub)[(size_t)wv * 16 + sl];
      r[0] -= bf2f(p.x & 0xffffu); r[1] -= bf2f(p.x >> 16);
      r[2] -= bf2f(p.y & 0xffffu); r[3] -= bf2f(p.y >> 16);
      r[4] -= bf2f(p.z & 0xffffu); r[5] -= bf2f(p.z >> 16);
      r[6] -= bf2f(p.w & 0xffffu); r[7] -= bf2f(p.w >> 16);
    }
    uint4 o;
    o.x = (unsigned)f2bf(r[0]) | ((unsigned)f2bf(r[1]) << 16);
    o.y = (unsigned)f2bf(r[2]) | ((unsigned)f2bf(r[3]) << 16);
    o.z = (unsigned)f2bf(r[4]) | ((unsigned)f2bf(r[5]) << 16);
    o.w = (unsigned)f2bf(r[6]) | ((unsigned)f2bf(r[7]) << 16);
    ((uint4*)Tout)[(size_t)wv * 16 + sl] = o;
  }
}

// ---------------- W transpose+convert: Wt[n][k*128 + r] = bf16(W[k][r][n]) ----------------
__global__ void convw_kernel(const float* __restrict__ W, unsigned short* __restrict__ Wt,
                             int total, int Kd) {
  int idx = blockIdx.x * 256 + threadIdx.x;
  if (idx >= total) return;
  int nn = idx / Kd;
  int rem = idx - nn * Kd;  // kk*128 + r
  int kk = rem >> 7;
  int r = rem & 127;
  Wt[idx] = f2bf(W[(size_t)kk * F * F + (size_t)r * F + nn]);
}

// ---------------- fused scale+GEMM ----------------
struct GemmArgs {
  const unsigned short* A[8];
  const float* fc;
  const unsigned short* Wt;
  const float* bias;
  float* out;
  int n;
  int kslices;
};

__global__ __launch_bounds__(256) void gemm_kernel(GemmArgs args) {
  __shared__ __align__(16) unsigned short lds_a[128][72];  // +8 pad
  __shared__ __align__(16) unsigned short lds_b[128][72];
  const int t = threadIdx.x;
  const int lane = t & 63;
  const int wid = t >> 6;
  const int wrow = wid >> 1, wcol = wid & 1;  // 2x2 waves, each 64x64
  const int bm = blockIdx.x * 128;
  const int n = args.n;
  const int kiters = args.kslices * 2;        // BK=64
  const int pitchW = args.kslices * 128;

  const int srow = t >> 4;        // 0..15
  const int scol = (t & 15) * 4;  // 0..60

  f32x4 acc[4][4];
#pragma unroll
  for (int a = 0; a < 4; ++a)
#pragma unroll
    for (int b = 0; b < 4; ++b) acc[a][b] = (f32x4){0.f, 0.f, 0.f, 0.f};

  for (int it = 0; it < kiters; ++it) {
    __syncthreads();
    const int ks = it >> 1;
    const unsigned short* As = args.A[ks];
    const float* fcs = args.fc + (size_t)ks * n;
    const int cbase = (it & 1) * 64 + scol;
#pragma unroll
    for (int i = 0; i < 8; ++i) {
      int r = srow + 16 * i;
      int rg = bm + r;
      int rc = rg < n ? rg : n - 1;
      u16x4 v = *(const u16x4*)(As + (size_t)rc * F + cbase);
      float f = fcs[rc];
      u16x4 sv;
      sv.x = f2bf(bf2f(v.x) * f);
      sv.y = f2bf(bf2f(v.y) * f);
      sv.z = f2bf(bf2f(v.z) * f);
      sv.w = f2bf(bf2f(v.w) * f);
      *(u16x4*)&lds_a[r][scol] = sv;
    }
    {
      const unsigned short* Ws = args.Wt + it * 64;
#pragma unroll
      for (int i = 0; i < 8; ++i) {
        int r = srow + 16 * i;
        u16x4 w = *(const u16x4*)(Ws + (size_t)r * pitchW + scol);
        *(u16x4*)&lds_b[r][scol] = w;
      }
    }
    __syncthreads();
#pragma unroll
    for (int kk = 0; kk < 2; ++kk) {
      s16x8 af[4], bfr[4];
#pragma unroll
      for (int mt = 0; mt < 4; ++mt)
        af[mt] = *(const s16x8*)&lds_a[wrow * 64 + mt * 16 + (lane & 15)][kk * 32 + (lane >> 4) * 8];
#pragma unroll
      for (int nt = 0; nt < 4; ++nt)
        bfr[nt] = *(const s16x8*)&lds_b[wcol * 64 + nt * 16 + (lane & 15)][kk * 32 + (lane >> 4) * 8];
#pragma unroll
      for (int mt = 0; mt < 4; ++mt)
#pragma unroll
        for (int nt = 0; nt < 4; ++nt)
          acc[mt][nt] = __builtin_amdgcn_mfma_f32_16x16x32_bf16(af[mt], bfr[nt], acc[mt][nt], 0, 0, 0);
    }
  }

#pragma unroll
  for (int nt = 0; nt < 4; ++nt) {
    int col = wcol * 64 + nt * 16 + (lane & 15);
    float bv = args.bias[col];
#pragma unroll
    for (int mt = 0; mt < 4; ++mt) {
#pragma unroll
      for (int r4 = 0; r4 < 4; ++r4) {
        int row = bm + wrow * 64 + mt * 16 + (lane >> 4) * 4 + r4;
        if (row < n) args.out[(size_t)row * F + col] = acc[mt][nt][r4] + bv;
      }
    }
  }
}

extern "C" void kernel_launch(void* const* d_in, const int* in_sizes, int n_in,
                              void* d_out, int out_size, void* d_ws, size_t ws_size,
                              hipStream_t stream) {
  const float* x    = (const float*)d_in[0];
  const float* fc   = (const float*)d_in[1];
  const float* W    = (const float*)d_in[2];
  const float* bias = (const float*)d_in[3];
  const float* ew   = (const float*)d_in[4];
  const int*   src  = (const int*)d_in[5];
  const int*   dst  = (const int*)d_in[6];

  const int N = in_sizes[0] / F;
  const int K = in_sizes[2] / (F * F);
  const int E = in_sizes[4];
  const int B = (N + BROWS - 1) >> BSHIFT;   // buckets; requires N <= 131072

  size_t off = 0;
  char* base = (char*)d_ws;
  auto alloc = [&](size_t bytes) -> void* {
    void* p = base + off;
    off += (bytes + 511) & ~(size_t)511;
    return p;
  };
  int* rp              = (int*)alloc(((size_t)N + 1) * 4);
  int* bhist           = (int*)alloc(1024);
  int* bbase           = (int*)alloc(1040);
  int* bcursor         = (int*)alloc(1024);
  int2* csr            = (int2*)alloc((size_t)E * 8);
  unsigned short* Wt   = (unsigned short*)alloc((size_t)K * F * F * 2);
  unsigned short* xbf  = (unsigned short*)alloc((size_t)N * F * 2);
  unsigned short* T[8];
  T[0] = xbf;
  for (int k = 1; k < K && k < 8; ++k) T[k] = (unsigned short*)alloc((size_t)N * F * 2);
  // staging aliased onto T[2] (written only after CSR build); fallback alloc if K<3
  unsigned int* stg_p;
  float* stg_w;
  if (K >= 3 && (size_t)N * F * 2 >= (size_t)E * 8) {
    stg_p = (unsigned int*)T[2];
    stg_w = (float*)(T[2] + (size_t)E * 2);  // E*2 ushorts == E*4 bytes
  } else {
    stg_p = (unsigned int*)alloc((size_t)E * 4);
    stg_w = (float*)alloc((size_t)E * 4);
  }
  if (off > ws_size) {
    fprintf(stderr, "kernel_launch: ws too small: need %zu have %zu\n", off, ws_size);
    return;
  }

  // ---- CSR build (bucketed) ----
  hipMemsetAsync(bhist, 0, 1024, stream);
  int hblocks = (E + 255) / 256;
  if (hblocks > 2048) hblocks = 2048;
  hipLaunchKernelGGL(bucket_hist_kernel, dim3(hblocks), dim3(256), 0, stream, dst, bhist, E, B);
  hipLaunchKernelGGL(bucket_scan_kernel, dim3(1), dim3(256), 0, stream, bhist, bbase, bcursor,
                     rp, E, B, N);
  int sblocks = (E + C2 - 1) / C2;
  hipLaunchKernelGGL(bucket_scatter_kernel, dim3(sblocks), dim3(256), 0, stream, src, dst, ew,
                     bcursor, stg_p, stg_w, E, B);
  hipLaunchKernelGGL(csr_build_kernel, dim3(B), dim3(256), 0, stream, stg_p, stg_w, bbase,
                     rp, csr, N, B);

  // ---- x -> bf16 ----
  int total4 = N * F / 4;
  hipLaunchKernelGGL(convx_kernel, dim3((total4 + 255) / 256), dim3(256), 0, stream,
                     x, xbf, total4);

  // ---- Chebyshev recurrence (bf16 state, fp32 accum) ----
  int sb = (N + 3) / 4;  // 4 waves (rows) per 256-thread block
  if (K > 1)
    hipLaunchKernelGGL(spmm_kernel, dim3(sb), dim3(256), 0, stream, xbf,
                       (const unsigned short*)nullptr, T[1], rp, csr, N, 1.0f);
  for (int k = 2; k < K; ++k) {
    const unsigned short* prev = T[k - 2];
    hipLaunchKernelGGL(spmm_kernel, dim3(sb), dim3(256), 0, stream, T[k - 1], prev, T[k],
                       rp, csr, N, 2.0f);
  }

  // ---- W transpose+convert ----
  int total = K * F * F;
  hipLaunchKernelGGL(convw_kernel, dim3((total + 255) / 256), dim3(256), 0, stream, W, Wt,
                     total, K * F);

  // ---- fused GEMM ----
  GemmArgs ga;
  for (int k = 0; k < 8; ++k) ga.A[k] = (k < K) ? T[k] : xbf;
  ga.fc = fc; ga.Wt = Wt; ga.bias = bias;
  ga.out = (float*)d_out;
  ga.n = N; ga.kslices = K;
  hipLaunchKernelGGL(gemm_kernel, dim3((N + 127) / 128), dim3(256), 0, stream, ga);
}